// Round 2
// baseline (793.096 us; speedup 1.0000x reference)
//
#include <hip/hip_runtime.h>
#include <hip/hip_bf16.h>
#include <stdint.h>

// Shapes (hard-coded for this problem)
#define T_  4
#define B_  64
#define C_  384
#define N_  196        // H*W = 14*14
#define NH  8
#define DH  48
#define TB_ (T_*B_)          // 256
#define R_  (T_*B_*N_)       // 50176 pixels total
#define NW  12               // 384 bits -> 12 u32 words per pixel
#define PBLK 784             // conv/stats blocks; 50176 = 784*64 pixels

typedef float f32x2 __attribute__((ext_vector_type(2)));

// ---------------------------------------------------------------------------
// K0: transpose all 4 weights W[o][c] -> WT[m][c][o]
__global__ void transpose_w4(const float* __restrict__ s0, const float* __restrict__ s1,
                             const float* __restrict__ s2, const float* __restrict__ s3,
                             float* __restrict__ dst){
    int m = blockIdx.y;
    const float* src = (m==0)?s0:(m==1)?s1:(m==2)?s2:s3;
    int idx = blockIdx.x*256 + threadIdx.x;
    if (idx >= C_*C_) return;
    int o = idx % C_, c = idx / C_;
    dst[(size_t)m*C_*C_ + idx] = src[o*C_ + c];
}

// ---------------------------------------------------------------------------
// K1: pre-LIF on raw x -> spike bitmask [t][b][n][12 words]
__global__ __launch_bounds__(256) void pre_lif(const float* __restrict__ x,
                                               uint32_t* __restrict__ maskXS){
    int b = blockIdx.x / NW;
    int w = blockIdx.x % NW;
    int n = threadIdx.x;
    if (n >= N_) return;
    float v[32];
#pragma unroll
    for (int j=0;j<32;j++) v[j] = 0.f;
#pragma unroll
    for (int t=0;t<T_;t++){
        uint32_t word = 0;
#pragma unroll
        for (int j=0;j<32;j++){
            int c = w*32 + j;
            float xv = x[((size_t)(t*B_+b)*C_ + c)*N_ + n];
            v[j] = 0.5f*(v[j] + xv);
            if (v[j] >= 1.0f){ word |= (1u<<j); v[j] = 0.f; }
        }
        maskXS[((size_t)(t*B_+b)*N_ + n)*NW + w] = word;
    }
}

// ---------------------------------------------------------------------------
// K2: sparse 1x1 conv + fused BN partial stats.
// Block = 64 pixels (4 waves x 16). Lane owns 6 contiguous outputs (o=6*lane..+5).
__global__ __launch_bounds__(256) void conv_stats(const uint32_t* __restrict__ mask,
                                                  const float* __restrict__ WT,
                                                  float* __restrict__ Y,
                                                  float* __restrict__ p1,
                                                  float* __restrict__ p2){
    __shared__ float red[2*C_];
    int tid = threadIdx.x, wave = tid>>6, lane = tid&63;
    for (int i=tid;i<2*C_;i+=256) red[i]=0.f;
    __syncthreads();
    int ob = 6*lane;
    f32x2 s1a={0.f,0.f}, s1b={0.f,0.f}, s1c={0.f,0.f};
    f32x2 s2a={0.f,0.f}, s2b={0.f,0.f}, s2c={0.f,0.f};
    for (int p=0;p<16;p++){
        int pix = blockIdx.x*64 + wave*16 + p;
        const uint32_t* mw = mask + (size_t)pix*NW;
        f32x2 y0={0.f,0.f}, y1={0.f,0.f}, y2={0.f,0.f};
#pragma unroll
        for (int w=0;w<NW;w++){
            uint32_t bits = mw[w];
            while (bits){
                int c = (w<<5) + __builtin_ctz(bits);
                bits &= bits - 1;
                const f32x2* col = (const f32x2*)(WT + (size_t)c*C_ + ob);
                y0 += col[0]; y1 += col[1]; y2 += col[2];
            }
        }
        s1a += y0; s1b += y1; s1c += y2;
        s2a += y0*y0; s2b += y1*y1; s2c += y2*y2;
        f32x2* yo = (f32x2*)(Y + (size_t)pix*C_ + ob);
        yo[0]=y0; yo[1]=y1; yo[2]=y2;
    }
    atomicAdd(&red[ob+0], s1a.x); atomicAdd(&red[ob+1], s1a.y);
    atomicAdd(&red[ob+2], s1b.x); atomicAdd(&red[ob+3], s1b.y);
    atomicAdd(&red[ob+4], s1c.x); atomicAdd(&red[ob+5], s1c.y);
    atomicAdd(&red[C_+ob+0], s2a.x); atomicAdd(&red[C_+ob+1], s2a.y);
    atomicAdd(&red[C_+ob+2], s2b.x); atomicAdd(&red[C_+ob+3], s2b.y);
    atomicAdd(&red[C_+ob+4], s2c.x); atomicAdd(&red[C_+ob+5], s2c.y);
    __syncthreads();
    for (int i=tid;i<C_;i+=256){
        p1[(size_t)blockIdx.x*C_ + i] = red[i];
        p2[(size_t)blockIdx.x*C_ + i] = red[C_+i];
    }
}

// ---------------------------------------------------------------------------
// K3: finalize BN -> fused scale/shift
__global__ __launch_bounds__(384) void stats_final(const float* __restrict__ p1,
                                                   const float* __restrict__ p2,
                                                   const float* __restrict__ g,
                                                   const float* __restrict__ bta,
                                                   float* __restrict__ scale,
                                                   float* __restrict__ shift){
    int o = threadIdx.x;
    float s1 = 0.f, s2 = 0.f;
    for (int b=0;b<PBLK;b++){ s1 += p1[b*C_+o]; s2 += p2[b*C_+o]; }
    float m   = s1 / (float)R_;
    float var = s2 / (float)R_ - m*m;
    float sc  = g[o] / sqrtf(var + 1e-5f);
    scale[o] = sc;
    shift[o] = bta[o] - m*sc;
}

// ---------------------------------------------------------------------------
// K4: LIF over normalized y, pack spikes into bitmask via ballot
__global__ __launch_bounds__(384) void lif_pack(const float* __restrict__ Y,
                                                const float* __restrict__ scale,
                                                const float* __restrict__ shift,
                                                uint32_t* __restrict__ maskOut){
    int pix0 = blockIdx.x;            // b*N_ + n
    int o = threadIdx.x;
    float sc = scale[o];
    float sh = shift[o];
    int w = o >> 6, lane = o & 63;
    float v = 0.f;
#pragma unroll
    for (int t=0;t<T_;t++){
        size_t pix = (size_t)t*B_*N_ + pix0;
        float y = Y[pix*C_ + o]*sc + sh;
        v = 0.5f*(v + y);
        int s = (v >= 1.0f);
        unsigned long long bal = __ballot(s);
        if (s) v = 0.f;
        if (lane == 0){
            maskOut[pix*NW + 2*w    ] = (uint32_t)bal;
            maskOut[pix*NW + 2*w + 1] = (uint32_t)(bal >> 32);
        }
    }
}

// ---------------------------------------------------------------------------
// K5: spiking attention fused with attn_lif (vth=0.5), exact integer path.
// grid = b*8 + h ; loop t inside; LIF membrane in registers; emits spike mask.
__global__ __launch_bounds__(256) void attention_lif(const uint32_t* __restrict__ mq,
                                                     const uint32_t* __restrict__ mk,
                                                     const uint32_t* __restrict__ mv,
                                                     uint16_t* __restrict__ mo){
    __shared__ unsigned long long kS[N_];
    __shared__ unsigned long long vT[DH][4];        // per-d bitmask over m
    __shared__ uint32_t sRow[N_*51];                // u8 S values, 4-packed, stride 51

    int id = blockIdx.x;
    int h  = id & 7;
    int b  = id >> 3;
    int tid = threadIdx.x;
    int sw  = (h*DH) >> 5;
    int shf = (h*DH) & 31;          // 0 or 16

    float vm[DH];
#pragma unroll
    for (int d=0;d<DH;d++) vm[d] = 0.f;

    for (int t=0;t<T_;t++){
        int tb = t*B_ + b;
        unsigned long long q = 0, vv = 0;
        if (tid < N_){
            const uint32_t* pq = mq + ((size_t)tb*N_ + tid)*NW + sw;
            const uint32_t* pk = mk + ((size_t)tb*N_ + tid)*NW + sw;
            const uint32_t* pv = mv + ((size_t)tb*N_ + tid)*NW + sw;
            unsigned long long lo, hi;
            lo = pq[0]; hi = pq[1];
            q  = (shf ? ((lo>>16) | (hi<<16)) : (lo | (hi<<32))) & 0xFFFFFFFFFFFFULL;
            lo = pk[0]; hi = pk[1];
            kS[tid] = (shf ? ((lo>>16) | (hi<<16)) : (lo | (hi<<32))) & 0xFFFFFFFFFFFFULL;
            lo = pv[0]; hi = pv[1];
            vv = (shf ? ((lo>>16) | (hi<<16)) : (lo | (hi<<32))) & 0xFFFFFFFFFFFFULL;
        }
        int wv = tid >> 6;
#pragma unroll 1
        for (int d=0; d<DH; d++){
            unsigned long long bal = __ballot((int)((vv>>d)&1ull));
            if ((tid & 63) == 0) vT[d][wv] = bal;
        }
        __syncthreads();

        if (tid < N_){
            for (int g4=0; g4<49; g4++){
                uint32_t pk = 0;
#pragma unroll
                for (int j=0;j<4;j++){
                    uint32_t s = (uint32_t)__popcll(q & kS[g4*4 + j]);
                    pk |= s << (8*j);
                }
                sRow[tid*51 + g4] = pk;
            }
        }
        __syncthreads();

        if (tid < N_){
            const uint32_t* myRow = &sRow[tid*51];
            unsigned long long sp = 0;
#pragma unroll
            for (int d=0; d<DH; d++){
                int a = 0;
#pragma unroll
                for (int w4=0; w4<4; w4++){
                    unsigned long long bb = vT[d][w4];   // uniform across lanes
                    while (bb){
                        int m = (w4<<6) + __builtin_ctzll(bb);
                        bb &= bb - 1;
                        a += (int)((myRow[m>>2] >> ((m&3)*8)) & 0xFF);
                    }
                }
                vm[d] = 0.5f*(vm[d] + 0.125f*(float)a);
                if (vm[d] >= 0.5f){ sp |= (1ull<<d); vm[d] = 0.f; }
            }
            size_t rec = ((size_t)tb*N_ + tid)*24 + 3*h;   // u16 index
            mo[rec]   = (uint16_t)(sp);
            mo[rec+1] = (uint16_t)(sp >> 16);
            mo[rec+2] = (uint16_t)(sp >> 32);
        }
        __syncthreads();
    }
}

// ---------------------------------------------------------------------------
// K6: final BN-normalize + layout transform [pix][c] -> [t,b,c,n]
__global__ __launch_bounds__(256) void final_norm(const float* __restrict__ Yp,
                                                  const float* __restrict__ scale,
                                                  const float* __restrict__ shift,
                                                  float* __restrict__ out){
    size_t idx = (size_t)blockIdx.x*256 + threadIdx.x;
    if (idx >= (size_t)R_*C_) return;
    int n  = (int)(idx % N_);
    int c  = (int)((idx / N_) % C_);
    int tb = (int)(idx / ((size_t)N_*C_));
    float y = Yp[((size_t)tb*N_ + n)*C_ + c];
    out[idx] = y*scale[c] + shift[c];
}

// ---------------------------------------------------------------------------
extern "C" void kernel_launch(void* const* d_in, const int* in_sizes, int n_in,
                              void* d_out, int out_size, void* d_ws, size_t ws_size,
                              hipStream_t stream) {
    const float* x  = (const float*)d_in[0];
    const float* Wq = (const float*)d_in[1];
    const float* Wk = (const float*)d_in[2];
    const float* Wv = (const float*)d_in[3];
    const float* Wp = (const float*)d_in[4];
    const float* gq = (const float*)d_in[5];
    const float* bq = (const float*)d_in[6];
    const float* gk = (const float*)d_in[7];
    const float* bk = (const float*)d_in[8];
    const float* gv = (const float*)d_in[9];
    const float* bv = (const float*)d_in[10];
    const float* gp = (const float*)d_in[11];
    const float* bp = (const float*)d_in[12];

    // workspace carve (~93 MB)
    char* w = (char*)d_ws;
    size_t off = 0;
    float* Ybuf = (float*)(w + off);  off += (size_t)R_*C_*4;        // 77 MB
    uint32_t* maskXS = (uint32_t*)(w + off); off += (size_t)R_*NW*4; // 2.4 MB each
    uint32_t* maskQ  = (uint32_t*)(w + off); off += (size_t)R_*NW*4;
    uint32_t* maskK  = (uint32_t*)(w + off); off += (size_t)R_*NW*4;
    uint32_t* maskV  = (uint32_t*)(w + off); off += (size_t)R_*NW*4;
    uint32_t* maskOL = (uint32_t*)(w + off); off += (size_t)R_*NW*4;
    float* WTall = (float*)(w + off); off += (size_t)4*C_*C_*4;      // 2.36 MB
    float* p1 = (float*)(w + off); off += (size_t)PBLK*C_*4;         // 1.2 MB
    float* p2 = (float*)(w + off); off += (size_t)PBLK*C_*4;
    float* scaleB = (float*)(w + off); off += C_*4;
    float* shiftB = (float*)(w + off); off += C_*4;

    transpose_w4<<<dim3((C_*C_+255)/256, 4),256,0,stream>>>(Wq, Wk, Wv, Wp, WTall);

    pre_lif<<<B_*NW,256,0,stream>>>(x, maskXS);

    const float* Gs[3] = {gq, gk, gv};
    const float* Bs[3] = {bq, bk, bv};
    uint32_t* Ms[3] = {maskQ, maskK, maskV};
    for (int i=0;i<3;i++){
        conv_stats<<<PBLK,256,0,stream>>>(maskXS, WTall + (size_t)i*C_*C_, Ybuf, p1, p2);
        stats_final<<<1,384,0,stream>>>(p1, p2, Gs[i], Bs[i], scaleB, shiftB);
        lif_pack<<<B_*N_,384,0,stream>>>(Ybuf, scaleB, shiftB, Ms[i]);
    }

    attention_lif<<<B_*NH,256,0,stream>>>(maskQ, maskK, maskV, (uint16_t*)maskOL);

    conv_stats<<<PBLK,256,0,stream>>>(maskOL, WTall + (size_t)3*C_*C_, Ybuf, p1, p2);
    stats_final<<<1,384,0,stream>>>(p1, p2, gp, bp, scaleB, shiftB);

    final_norm<<<(int)(((size_t)R_*C_ + 255)/256),256,0,stream>>>(Ybuf, scaleB, shiftB, (float*)d_out);
}

// Round 3
// 429.477 us; speedup vs baseline: 1.8467x; 1.8467x over previous
//
#include <hip/hip_runtime.h>
#include <hip/hip_bf16.h>
#include <stdint.h>

// Shapes (hard-coded for this problem)
#define T_  4
#define B_  64
#define C_  384
#define N_  196        // H*W = 14*14
#define NH  8
#define DH  48
#define TB_ (T_*B_)          // 256
#define R_  (T_*B_*N_)       // 50176 pixels total
#define NW  12               // 384 bits -> 12 u32 words per pixel
#define CBLK 12544           // conv blocks: 1 pixel per wave, 4 waves
#define SA_  64              // statsA blocks (each sums CBLK/SA_ = 196 rows)

typedef float f32x2 __attribute__((ext_vector_type(2)));

// ---------------------------------------------------------------------------
// K0: transpose all 4 weights W[o][c] -> WT[m][c][o]
__global__ void transpose_w4(const float* __restrict__ s0, const float* __restrict__ s1,
                             const float* __restrict__ s2, const float* __restrict__ s3,
                             float* __restrict__ dst){
    int m = blockIdx.y;
    const float* src = (m==0)?s0:(m==1)?s1:(m==2)?s2:s3;
    int idx = blockIdx.x*256 + threadIdx.x;
    if (idx >= C_*C_) return;
    int o = idx % C_, c = idx / C_;
    dst[(size_t)m*C_*C_ + idx] = src[o*C_ + c];
}

// ---------------------------------------------------------------------------
// K1: pre-LIF on raw x -> spike bitmask [t][b][n][12 words]
__global__ __launch_bounds__(256) void pre_lif(const float* __restrict__ x,
                                               uint32_t* __restrict__ maskXS){
    int b = blockIdx.x / NW;
    int w = blockIdx.x % NW;
    int n = threadIdx.x;
    if (n >= N_) return;
    float v[32];
#pragma unroll
    for (int j=0;j<32;j++) v[j] = 0.f;
#pragma unroll
    for (int t=0;t<T_;t++){
        uint32_t word = 0;
#pragma unroll
        for (int j=0;j<32;j++){
            int c = w*32 + j;
            float xv = x[((size_t)(t*B_+b)*C_ + c)*N_ + n];
            v[j] = v[j] + (xv - v[j])*0.5f;     // reference rounding order
            if (v[j] >= 1.0f){ word |= (1u<<j); v[j] = 0.f; }
        }
        maskXS[((size_t)(t*B_+b)*N_ + n)*NW + w] = word;
    }
}

// ---------------------------------------------------------------------------
// K2: sparse 1x1 conv + fused BN partials. 1 pixel per wave, grid CBLK.
// Lane owns 6 contiguous outputs. Two independent accumulator chains for ILP.
__global__ __launch_bounds__(256) void conv_stats(const uint32_t* __restrict__ mask,
                                                  const float* __restrict__ WT,
                                                  float* __restrict__ Y,
                                                  float* __restrict__ p1,
                                                  float* __restrict__ p2){
    __shared__ float red[4][C_];
    int tid = threadIdx.x, wave = tid>>6, lane = tid&63;
    int pix = blockIdx.x*4 + wave;
    int ob  = 6*lane;
    const uint4* m4 = (const uint4*)(mask + (size_t)pix*NW);
    uint4 ma = m4[0], mb = m4[1], mc = m4[2];
    uint32_t mwv[12] = {ma.x,ma.y,ma.z,ma.w, mb.x,mb.y,mb.z,mb.w, mc.x,mc.y,mc.z,mc.w};
    f32x2 y0={0.f,0.f}, y1={0.f,0.f}, y2={0.f,0.f};
    f32x2 z0={0.f,0.f}, z1={0.f,0.f}, z2={0.f,0.f};
#pragma unroll
    for (int w=0; w<NW; w++){
        uint32_t bits = mwv[w];
        while (bits){
            int c0 = (w<<5) + __builtin_ctz(bits); bits &= bits-1;
            const f32x2* col0 = (const f32x2*)(WT + (size_t)c0*C_ + ob);
            if (bits){
                int c1 = (w<<5) + __builtin_ctz(bits); bits &= bits-1;
                const f32x2* col1 = (const f32x2*)(WT + (size_t)c1*C_ + ob);
                f32x2 a0=col0[0],a1=col0[1],a2=col0[2];
                f32x2 b0=col1[0],b1=col1[1],b2=col1[2];
                y0+=a0; y1+=a1; y2+=a2;
                z0+=b0; z1+=b1; z2+=b2;
            } else {
                y0+=col0[0]; y1+=col0[1]; y2+=col0[2];
            }
        }
    }
    y0+=z0; y1+=z1; y2+=z2;
    f32x2* yo = (f32x2*)(Y + (size_t)pix*C_ + ob);
    yo[0]=y0; yo[1]=y1; yo[2]=y2;
    *(f32x2*)&red[wave][ob  ] = y0;
    *(f32x2*)&red[wave][ob+2] = y1;
    *(f32x2*)&red[wave][ob+4] = y2;
    __syncthreads();
    for (int i=tid; i<C_; i+=256){
        float v0=red[0][i], v1=red[1][i], v2=red[2][i], v3=red[3][i];
        p1[(size_t)blockIdx.x*C_ + i] = (v0+v1)+(v2+v3);
        p2[(size_t)blockIdx.x*C_ + i] = (v0*v0+v1*v1)+(v2*v2+v3*v3);
    }
}

// ---------------------------------------------------------------------------
// K3a: first-stage partial reduce (CBLK rows -> SA_ rows)
__global__ __launch_bounds__(384) void statsA(const float* __restrict__ p1,
                                              const float* __restrict__ p2,
                                              float* __restrict__ q1,
                                              float* __restrict__ q2){
    int o = threadIdx.x;
    int blk = blockIdx.x;
    const int ROWS = CBLK / SA_;   // 196
    size_t base = (size_t)blk*ROWS*C_ + o;
    float s1=0.f, s2=0.f;
#pragma unroll 4
    for (int r=0;r<ROWS;r++){
        s1 += p1[base + (size_t)r*C_];
        s2 += p2[base + (size_t)r*C_];
    }
    q1[blk*C_ + o] = s1;
    q2[blk*C_ + o] = s2;
}

// K3b: finalize BN -> fused scale/shift
__global__ __launch_bounds__(384) void statsB(const float* __restrict__ q1,
                                              const float* __restrict__ q2,
                                              const float* __restrict__ g,
                                              const float* __restrict__ bta,
                                              float* __restrict__ scale,
                                              float* __restrict__ shift){
    int o = threadIdx.x;
    float s1=0.f, s2=0.f;
#pragma unroll
    for (int b=0;b<SA_;b++){ s1 += q1[b*C_+o]; s2 += q2[b*C_+o]; }
    float m   = s1 / (float)R_;
    float var = s2 / (float)R_ - m*m;
    float sc  = g[o] / sqrtf(var + 1e-5f);
    scale[o] = sc;
    shift[o] = bta[o] - m*sc;
}

// ---------------------------------------------------------------------------
// K4: LIF over normalized y, pack spikes into bitmask via ballot
__global__ __launch_bounds__(384) void lif_pack(const float* __restrict__ Y,
                                                const float* __restrict__ scale,
                                                const float* __restrict__ shift,
                                                uint32_t* __restrict__ maskOut){
    int pix0 = blockIdx.x;            // b*N_ + n
    int o = threadIdx.x;
    float sc = scale[o];
    float sh = shift[o];
    int w = o >> 6, lane = o & 63;
    float v = 0.f;
#pragma unroll
    for (int t=0;t<T_;t++){
        size_t pix = (size_t)t*B_*N_ + pix0;
        float y = Y[pix*C_ + o]*sc + sh;
        v = v + (y - v)*0.5f;
        int s = (v >= 1.0f);
        unsigned long long bal = __ballot(s);
        if (s) v = 0.f;
        if (lane == 0){
            maskOut[pix*NW + 2*w    ] = (uint32_t)bal;
            maskOut[pix*NW + 2*w + 1] = (uint32_t)(bal >> 32);
        }
    }
}

// ---------------------------------------------------------------------------
// K5: spiking attention + attn_lif via the C = K^T V trick (exact integers).
// o[n,d] = sum_j q[n,j] * C[j,d],  C[j,d] = sum_m k[m,j] v[m,d] (popcounts).
__global__ __launch_bounds__(256) void attention_lif(const uint32_t* __restrict__ mq,
                                                     const uint32_t* __restrict__ mk,
                                                     const uint32_t* __restrict__ mv,
                                                     uint16_t* __restrict__ mo){
    __shared__ unsigned long long kT[DH][4];
    __shared__ unsigned long long vT[DH][4];
    __shared__ uint32_t Cp[DH*25];           // u16-pair packed C, row stride 25

    int h = blockIdx.x & 7;
    int b = blockIdx.x >> 3;
    int tid = threadIdx.x, wv = tid>>6, lane = tid&63;
    int sw  = (h*DH) >> 5;
    int shf = (h*DH) & 31;                   // 0 or 16

    float vm[DH];
#pragma unroll
    for (int d=0;d<DH;d++) vm[d] = 0.f;

    for (int t=0;t<T_;t++){
        int tb = t*B_ + b;
        unsigned long long q = 0, kk = 0, vvv = 0;
        if (tid < N_){
            const uint32_t* pq = mq + ((size_t)tb*N_ + tid)*NW + sw;
            const uint32_t* pk = mk + ((size_t)tb*N_ + tid)*NW + sw;
            const uint32_t* pv = mv + ((size_t)tb*N_ + tid)*NW + sw;
            unsigned long long lo, hi;
            lo = pq[0]; hi = pq[1];
            q   = (shf ? ((lo>>16) | (hi<<16)) : (lo | (hi<<32))) & 0xFFFFFFFFFFFFULL;
            lo = pk[0]; hi = pk[1];
            kk  = (shf ? ((lo>>16) | (hi<<16)) : (lo | (hi<<32))) & 0xFFFFFFFFFFFFULL;
            lo = pv[0]; hi = pv[1];
            vvv = (shf ? ((lo>>16) | (hi<<16)) : (lo | (hi<<32))) & 0xFFFFFFFFFFFFULL;
        }
#pragma unroll 1
        for (int d=0; d<DH; d++){
            unsigned long long bk_ = __ballot((int)((kk >>d)&1ull));
            unsigned long long bv_ = __ballot((int)((vvv>>d)&1ull));
            if (lane == 0){ kT[d][wv] = bk_; vT[d][wv] = bv_; }
        }
        __syncthreads();

        // C build: 240 threads, thread = (j, d-decile)
        if (tid < 240){
            int j  = tid / 5;
            int dg = tid % 5;
            int d0 = dg*10;
            int d1 = (dg==4) ? 48 : d0+10;
            unsigned long long ka=kT[j][0], kb=kT[j][1], kc=kT[j][2], kd=kT[j][3];
            for (int d=d0; d<d1; d+=2){
                uint32_t c0 = (uint32_t)(__popcll(ka&vT[d][0]) + __popcll(kb&vT[d][1])
                            + __popcll(kc&vT[d][2]) + __popcll(kd&vT[d][3]));
                uint32_t c1 = (uint32_t)(__popcll(ka&vT[d+1][0]) + __popcll(kb&vT[d+1][1])
                            + __popcll(kc&vT[d+1][2]) + __popcll(kd&vT[d+1][3]));
                Cp[j*25 + (d>>1)] = c0 | (c1<<16);
            }
        }
        __syncthreads();

        if (tid < N_){
            uint32_t acc[24];
#pragma unroll
            for (int p=0;p<24;p++) acc[p] = 0u;
            unsigned long long qb = q;
            while (qb){
                int j = __builtin_ctzll(qb); qb &= qb-1;
                const uint32_t* row = &Cp[j*25];
#pragma unroll
                for (int p=0;p<24;p++) acc[p] += row[p];
            }
            unsigned long long sp = 0;
#pragma unroll
            for (int d=0; d<DH; d++){
                uint32_t a = (d&1) ? (acc[d>>1]>>16) : (acc[d>>1]&0xFFFFu);
                float o = 0.125f*(float)a;
                vm[d] = vm[d] + (o - vm[d])*0.5f;
                if (vm[d] >= 0.5f){ sp |= (1ull<<d); vm[d] = 0.f; }
            }
            size_t rec = ((size_t)tb*N_ + tid)*24 + 3*h;   // u16 index
            mo[rec]   = (uint16_t)(sp);
            mo[rec+1] = (uint16_t)(sp >> 16);
            mo[rec+2] = (uint16_t)(sp >> 32);
        }
        __syncthreads();
    }
}

// ---------------------------------------------------------------------------
// K6: final BN-normalize + transpose [pix][c] -> [t,b,c,n] via LDS tile
__global__ __launch_bounds__(256) void final_norm(const float* __restrict__ Yp,
                                                  const float* __restrict__ scale,
                                                  const float* __restrict__ shift,
                                                  float* __restrict__ out){
    __shared__ float tile[98][65];
    int bid = blockIdx.x;
    int tb   = bid / 12;
    int r    = bid % 12;
    int c0   = (r>>1)*64;
    int n0   = (r&1)*98;
    int lane = threadIdx.x & 63, w = threadIdx.x >> 6;
    for (int n = w; n < 98; n += 4)
        tile[n][lane] = Yp[((size_t)tb*N_ + n0 + n)*C_ + c0 + lane];
    __syncthreads();
    for (int l = w; l < 64; l += 4){
        int c = c0 + l;
        float sc = scale[c], sh = shift[c];
        float* ob = out + ((size_t)tb*C_ + c)*N_ + n0;
        ob[lane] = tile[lane][l]*sc + sh;
        if (lane < 34) ob[64+lane] = tile[64+lane][l]*sc + sh;
    }
}

// ---------------------------------------------------------------------------
extern "C" void kernel_launch(void* const* d_in, const int* in_sizes, int n_in,
                              void* d_out, int out_size, void* d_ws, size_t ws_size,
                              hipStream_t stream) {
    const float* x  = (const float*)d_in[0];
    const float* Wq = (const float*)d_in[1];
    const float* Wk = (const float*)d_in[2];
    const float* Wv = (const float*)d_in[3];
    const float* Wp = (const float*)d_in[4];
    const float* gq = (const float*)d_in[5];
    const float* bq = (const float*)d_in[6];
    const float* gk = (const float*)d_in[7];
    const float* bk = (const float*)d_in[8];
    const float* gv = (const float*)d_in[9];
    const float* bv = (const float*)d_in[10];
    const float* gp = (const float*)d_in[11];
    const float* bp = (const float*)d_in[12];

    // workspace carve (~89 MB; conv partials live in d_out scratch)
    char* w = (char*)d_ws;
    size_t off = 0;
    float* Ybuf = (float*)(w + off);  off += (size_t)R_*C_*4;        // 77 MB
    uint32_t* maskXS = (uint32_t*)(w + off); off += (size_t)R_*NW*4; // 2.4 MB each
    uint32_t* maskQ  = (uint32_t*)(w + off); off += (size_t)R_*NW*4;
    uint32_t* maskK  = (uint32_t*)(w + off); off += (size_t)R_*NW*4;
    uint32_t* maskV  = (uint32_t*)(w + off); off += (size_t)R_*NW*4;
    float* WTall = (float*)(w + off); off += (size_t)4*C_*C_*4;      // 2.36 MB
    float* q1 = (float*)(w + off); off += (size_t)SA_*C_*4;
    float* q2 = (float*)(w + off); off += (size_t)SA_*C_*4;
    float* scaleB = (float*)(w + off); off += C_*4;
    float* shiftB = (float*)(w + off); off += C_*4;
    uint32_t* maskOL = maskXS;         // alias: XS dead after v-conv

    // conv partials staged in d_out (fully overwritten by final_norm later)
    float* p1 = (float*)d_out;                      // 19.3 MB
    float* p2 = ((float*)d_out) + (size_t)CBLK*C_;  // 19.3 MB

    transpose_w4<<<dim3((C_*C_+255)/256, 4),256,0,stream>>>(Wq, Wk, Wv, Wp, WTall);

    pre_lif<<<B_*NW,256,0,stream>>>(x, maskXS);

    const float* Gs[3] = {gq, gk, gv};
    const float* Bs[3] = {bq, bk, bv};
    uint32_t* Ms[3] = {maskQ, maskK, maskV};
    for (int i=0;i<3;i++){
        conv_stats<<<CBLK,256,0,stream>>>(maskXS, WTall + (size_t)i*C_*C_, Ybuf, p1, p2);
        statsA<<<SA_,384,0,stream>>>(p1, p2, q1, q2);
        statsB<<<1,384,0,stream>>>(q1, q2, Gs[i], Bs[i], scaleB, shiftB);
        lif_pack<<<B_*N_,384,0,stream>>>(Ybuf, scaleB, shiftB, Ms[i]);
    }

    attention_lif<<<B_*NH,256,0,stream>>>(maskQ, maskK, maskV, (uint16_t*)maskOL);

    conv_stats<<<CBLK,256,0,stream>>>(maskOL, WTall + (size_t)3*C_*C_, Ybuf, p1, p2);
    statsA<<<SA_,384,0,stream>>>(p1, p2, q1, q2);
    statsB<<<1,384,0,stream>>>(q1, q2, gp, bp, scaleB, shiftB);

    final_norm<<<TB_*12,256,0,stream>>>(Ybuf, scaleB, shiftB, (float*)d_out);
}